// Round 1
// baseline (1264.326 us; speedup 1.0000x reference)
//
#include <hip/hip_runtime.h>
#include <hip/hip_bf16.h>
#include <math.h>

// MultiLayerGRUParallel: B=32, S=4096, H=128, OUT=128, L=3
// Pipeline: prep0 -> scan(3 pass) -> [convw -> mmprep -> scan]x2 -> outmm -> outred
#define B_   32
#define S_   4096
#define H_   128
#define OUT_ 128
#define P_   (B_*S_)       // 131072 positions
#define NC_  64            // time chunks per chain
#define CH_  (S_/NC_)      // 64 steps per chunk
#define NKS_ 512           // split-K workgroups for final matmul
#define KTOT_ (H_*S_)      // 524288

typedef __bf16 bf16x8 __attribute__((ext_vector_type(8)));
typedef float  f32x4  __attribute__((ext_vector_type(4)));
typedef unsigned short ushort8_t __attribute__((ext_vector_type(8)));

__device__ __forceinline__ float sp_(float x) {           // softplus, stable
  return fmaxf(x, 0.f) + log1pf(__expf(-fabsf(x)));
}
__device__ __forceinline__ float logg_(float x) {          // _log_g
  return (x >= 0.f) ? __logf(x + 0.5f) : -sp_(-x);
}
__device__ __forceinline__ float lae_(float a, float b) {  // logaddexp
  float m = fmaxf(a, b);
  float d = fminf(a, b) - m;           // -inf ok: exp(-inf)=0
  return m + log1pf(__expf(d));
}
__device__ __forceinline__ unsigned short f2bf_(float f) { // fp32->bf16 RNE
  unsigned int u = __float_as_uint(f);
  u += 0x7fffu + ((u >> 16) & 1u);
  return (unsigned short)(u >> 16);
}
__device__ __forceinline__ float wscan_(float v) {         // wave64 inclusive +scan
  int lane = threadIdx.x & 63;
  #pragma unroll
  for (int d = 1; d < 64; d <<= 1) {
    float t = __shfl_up(v, (unsigned)d, 64);
    if (lane >= d) v += t;
  }
  return v;
}

// ---------------- layer 0 prep (din=1, elementwise) ----------------
// block=128 (2 waves), each wave owns one position: ch = lane and lane+64.
__global__ __launch_bounds__(128) void prep0_kernel(
    const float* __restrict__ x,
    const float* __restrict__ Wz, const float* __restrict__ bz,
    const float* __restrict__ Wh, const float* __restrict__ bh,
    float* __restrict__ u, float* __restrict__ A)
{
  int lane = threadIdx.x & 63;
  int wid  = threadIdx.x >> 6;  // 0/1
  float wz0 = Wz[lane], wz1 = Wz[lane + 64];
  float bz0 = bz[lane], bz1 = bz[lane + 64];
  float wh0 = Wh[lane], wh1 = Wh[lane + 64];
  float bh0 = bh[lane], bh1 = bh[lane + 64];
  int base = blockIdx.x * 16;
  for (int i = 0; i < 8; ++i) {
    int pos = base + i * 2 + wid;
    float xv = x[pos];
    float k0 = xv * wz0 + bz0, k1 = xv * wz1 + bz1;
    float g0 = xv * wh0 + bh0, g1 = xv * wh1 + bh1;
    float lc0 = -sp_(k0), lc1 = -sp_(k1);
    float lv0 = -sp_(-k0) + logg_(g0);
    float lv1 = -sp_(-k1) + logg_(g1);
    float s0 = wscan_(lc0);
    float t0 = __shfl(s0, 63, 64);
    float s1 = wscan_(lc1) + t0;
    size_t o = (size_t)pos * H_;
    u[o + lane]      = lv0 - s0;
    u[o + 64 + lane] = lv1 - s1;
    A[o + lane]      = s0;
    A[o + 64 + lane] = s1;
  }
}

// ---------------- chunked logaddexp scan over time ----------------
__global__ __launch_bounds__(128) void scan1_kernel(
    const float* __restrict__ u, float* __restrict__ tot)
{
  int b = blockIdx.x / NC_, c = blockIdx.x % NC_, ch = threadIdx.x;
  const float* up = u + (size_t)(b * S_ + c * CH_) * H_ + ch;
  float r = -__builtin_inff();
  for (int i = 0; i < CH_; ++i) r = lae_(r, up[(size_t)i * H_]);
  tot[(size_t)blockIdx.x * H_ + ch] = r;
}

__global__ __launch_bounds__(128) void scan2_kernel(
    const float* __restrict__ tot, float* __restrict__ carry)
{
  int b = blockIdx.x, ch = threadIdx.x;
  float r = -0.6931471805599453f;  // log(0.5): the t=0 init value
  for (int c = 0; c < NC_; ++c) {
    size_t idx = (size_t)(b * NC_ + c) * H_ + ch;
    carry[idx] = r;
    r = lae_(r, tot[idx]);
  }
}

__global__ __launch_bounds__(128) void scan3_kernel(
    const float* __restrict__ u, const float* __restrict__ A,
    const float* __restrict__ carry, unsigned short* __restrict__ hbf)
{
  int b = blockIdx.x / NC_, c = blockIdx.x % NC_, ch = threadIdx.x;
  size_t pbase = (size_t)(b * S_ + c * CH_) * H_ + ch;
  float r = carry[(size_t)blockIdx.x * H_ + ch];
  for (int i = 0; i < CH_; ++i) {
    size_t o = pbase + (size_t)i * H_;
    r = lae_(r, u[o]);
    float logh = A[o] + r;
    float e = __expf(logh);
    float hv = 1.f / (1.f + __expf(-e));   // sigmoid(exp(log_h))
    hbf[o] = f2bf_(hv);
  }
}

// ---------------- weight convert: [Wz;Wh] -> bf16 256x128 ----------------
__global__ __launch_bounds__(256) void convw_kernel(
    const float* __restrict__ Wz, const float* __restrict__ Wh,
    unsigned short* __restrict__ Wc)
{
  int idx = blockIdx.x * 256 + threadIdx.x;  // < 32768
  float v = (idx < 16384) ? Wz[idx] : Wh[idx - 16384];
  Wc[idx] = f2bf_(v);
}

// ---------------- fused dual matmul (k|g) + elementwise + channel prefix ----
// block=256 (4 waves). Wave w owns output cols [64w,64w+64) of N=256 ([k|g]).
// 64 rows per block in 4 tiles of 16. MFMA 16x16x32 bf16.
__global__ __launch_bounds__(256) void mmprep_kernel(
    const unsigned short* __restrict__ hbf,   // P x 128 bf16
    const unsigned short* __restrict__ Wc,    // 256 x 128 bf16
    const float* __restrict__ bz, const float* __restrict__ bh,
    float* __restrict__ u, float* __restrict__ A)
{
  __shared__ float kg[16][260];
  int tid = threadIdx.x;
  int w = tid >> 6, lane = tid & 63;
  int l15 = lane & 15, quad = lane >> 4;

  // B-frags: b[lane][j] = B[k=quad*8+j][n=lane&15], B[k][n] = Wc[n][k]
  bf16x8 bfrag[4][4];  // [kk][nt]
  #pragma unroll
  for (int nt = 0; nt < 4; ++nt) {
    int wrow = w * 64 + nt * 16 + l15;
    #pragma unroll
    for (int kk = 0; kk < 4; ++kk)
      bfrag[kk][nt] = *reinterpret_cast<const bf16x8*>(
          Wc + wrow * 128 + kk * 32 + quad * 8);
  }
  float bz0v = bz[lane], bz1v = bz[lane + 64];
  float bh0v = bh[lane], bh1v = bh[lane + 64];

  int row0_base = blockIdx.x * 64;
  for (int t = 0; t < 4; ++t) {
    int row0 = row0_base + t * 16;
    f32x4 acc[4] = {{0,0,0,0},{0,0,0,0},{0,0,0,0},{0,0,0,0}};
    #pragma unroll
    for (int kk = 0; kk < 4; ++kk) {
      // A-frag: a[lane][j] = A[m=lane&15][k=quad*8+j]
      bf16x8 a = *reinterpret_cast<const bf16x8*>(
          hbf + (size_t)(row0 + l15) * 128 + kk * 32 + quad * 8);
      #pragma unroll
      for (int nt = 0; nt < 4; ++nt)
        acc[nt] = __builtin_amdgcn_mfma_f32_16x16x32_bf16(a, bfrag[kk][nt], acc[nt], 0, 0, 0);
    }
    __syncthreads();  // previous epilogue done reading LDS
    #pragma unroll
    for (int nt = 0; nt < 4; ++nt) {
      int col = w * 64 + nt * 16 + l15;
      #pragma unroll
      for (int r = 0; r < 4; ++r)
        kg[quad * 4 + r][col] = acc[nt][r];  // D: row=quad*4+r, col=lane&15
    }
    __syncthreads();
    // epilogue: wave w handles rows w, w+4, w+8, w+12; one full row per wave
    #pragma unroll
    for (int i = 0; i < 4; ++i) {
      int row = w + i * 4;
      int p = row0 + row;
      float k0 = kg[row][lane]       + bz0v;
      float k1 = kg[row][64 + lane]  + bz1v;
      float g0 = kg[row][128 + lane] + bh0v;
      float g1 = kg[row][192 + lane] + bh1v;
      float lc0 = -sp_(k0), lc1 = -sp_(k1);
      float lv0 = -sp_(-k0) + logg_(g0);
      float lv1 = -sp_(-k1) + logg_(g1);
      float s0 = wscan_(lc0);
      float t0 = __shfl(s0, 63, 64);
      float s1 = wscan_(lc1) + t0;
      size_t o = (size_t)p * H_;
      u[o + lane]      = lv0 - s0;
      u[o + 64 + lane] = lv1 - s1;
      A[o + lane]      = s0;
      A[o + 64 + lane] = s1;
    }
  }
}

// ---------------- final matmul: out[32,128] = h2flat @ Wout^T + bout --------
// split-K: each WG handles K-slice of KTOT_/NKS_; partials to ws, reduce after.
__global__ __launch_bounds__(256) void outmm_kernel(
    const unsigned short* __restrict__ hbf,  // 32 x 524288 bf16
    const float* __restrict__ Wout,          // 128 x 524288 fp32
    float* __restrict__ part)
{
  const int KSL = KTOT_ / NKS_;  // 1024
  int tid = threadIdx.x, w = tid >> 6, lane = tid & 63;
  int l15 = lane & 15, quad = lane >> 4;
  int k0base = blockIdx.x * KSL;
  f32x4 acc[2][2] = {{{0,0,0,0},{0,0,0,0}},{{0,0,0,0},{0,0,0,0}}};
  for (int ks = 0; ks < KSL; ks += 32) {
    int k0 = k0base + ks;
    bf16x8 a0 = *reinterpret_cast<const bf16x8*>(
        hbf + (size_t)l15 * KTOT_ + k0 + quad * 8);
    bf16x8 a1 = *reinterpret_cast<const bf16x8*>(
        hbf + (size_t)(16 + l15) * KTOT_ + k0 + quad * 8);
    #pragma unroll
    for (int nt = 0; nt < 2; ++nt) {
      int n = w * 32 + nt * 16 + l15;
      const float* wp = Wout + (size_t)n * KTOT_ + k0 + quad * 8;
      float4 wa = *reinterpret_cast<const float4*>(wp);
      float4 wb = *reinterpret_cast<const float4*>(wp + 4);
      ushort8_t tt;
      tt[0] = f2bf_(wa.x); tt[1] = f2bf_(wa.y); tt[2] = f2bf_(wa.z); tt[3] = f2bf_(wa.w);
      tt[4] = f2bf_(wb.x); tt[5] = f2bf_(wb.y); tt[6] = f2bf_(wb.z); tt[7] = f2bf_(wb.w);
      bf16x8 bf = __builtin_bit_cast(bf16x8, tt);
      acc[0][nt] = __builtin_amdgcn_mfma_f32_16x16x32_bf16(a0, bf, acc[0][nt], 0, 0, 0);
      acc[1][nt] = __builtin_amdgcn_mfma_f32_16x16x32_bf16(a1, bf, acc[1][nt], 0, 0, 0);
    }
  }
  float* pp = part + (size_t)blockIdx.x * (B_ * OUT_);
  #pragma unroll
  for (int mt = 0; mt < 2; ++mt)
    #pragma unroll
    for (int nt = 0; nt < 2; ++nt)
      #pragma unroll
      for (int r = 0; r < 4; ++r) {
        int b = mt * 16 + quad * 4 + r;
        int o = w * 32 + nt * 16 + l15;
        pp[b * OUT_ + o] = acc[mt][nt][r];
      }
}

__global__ __launch_bounds__(256) void outred_kernel(
    const float* __restrict__ part, const float* __restrict__ bout,
    float* __restrict__ out)
{
  int idx = blockIdx.x * 256 + threadIdx.x;  // < 4096
  float s = bout[idx & (OUT_ - 1)];
  for (int wg = 0; wg < NKS_; ++wg) s += part[(size_t)wg * (B_ * OUT_) + idx];
  out[idx] = s;
}

// ---------------- host launcher ----------------
extern "C" void kernel_launch(void* const* d_in, const int* in_sizes, int n_in,
                              void* d_out, int out_size, void* d_ws, size_t ws_size,
                              hipStream_t stream)
{
  const float* x    = (const float*)d_in[0];
  const float* Wz[3] = {(const float*)d_in[1], (const float*)d_in[5], (const float*)d_in[9]};
  const float* bz[3] = {(const float*)d_in[2], (const float*)d_in[6], (const float*)d_in[10]};
  const float* Wh[3] = {(const float*)d_in[3], (const float*)d_in[7], (const float*)d_in[11]};
  const float* bh[3] = {(const float*)d_in[4], (const float*)d_in[8], (const float*)d_in[12]};
  const float* Wout = (const float*)d_in[13];
  const float* bout = (const float*)d_in[14];
  float* out = (float*)d_out;

  char* ws = (char*)d_ws;
  float*          u     = (float*)(ws + 0);                  // 64 MiB
  float*          A     = (float*)(ws + 67108864);           // 64 MiB
  unsigned short* hbf   = (unsigned short*)(ws + 134217728); // 32 MiB
  unsigned short* Wc    = (unsigned short*)(ws + 167772160); // 64 KiB
  float*          tot   = (float*)(ws + 167837696);          // 1 MiB
  float*          carry = (float*)(ws + 168886272);          // 1 MiB
  float*          part  = (float*)(ws + 169934848);          // 8 MiB -> end 178323456

  // layer 0
  prep0_kernel<<<P_ / 16, 128, 0, stream>>>(x, Wz[0], bz[0], Wh[0], bh[0], u, A);
  scan1_kernel<<<B_ * NC_, 128, 0, stream>>>(u, tot);
  scan2_kernel<<<B_, 128, 0, stream>>>(tot, carry);
  scan3_kernel<<<B_ * NC_, 128, 0, stream>>>(u, A, carry, hbf);

  // layers 1, 2
  for (int l = 1; l <= 2; ++l) {
    convw_kernel<<<128, 256, 0, stream>>>(Wz[l], Wh[l], Wc);
    mmprep_kernel<<<P_ / 64, 256, 0, stream>>>(hbf, Wc, bz[l], bh[l], u, A);
    scan1_kernel<<<B_ * NC_, 128, 0, stream>>>(u, tot);
    scan2_kernel<<<B_, 128, 0, stream>>>(tot, carry);
    scan3_kernel<<<B_ * NC_, 128, 0, stream>>>(u, A, carry, hbf);
  }

  // output head
  outmm_kernel<<<NKS_, 256, 0, stream>>>(hbf, Wout, part);
  outred_kernel<<<(B_ * OUT_) / 256, 256, 0, stream>>>(part, bout, out);
}